// Round 10
// baseline (838.787 us; speedup 1.0000x reference)
//
#include <hip/hip_runtime.h>
#include <hip/hip_bf16.h>

// InstanSeg v9: fix pix occupancy/balance (v8 post-mortem: 8.9% occupancy,
// 1152 blocks with 8x work variance -> tail-bound).
//  pix: 1-wave blocks (4608), center-out row dispatch, b2 folded into the
//       packed-f16 epilogue, 2-stage D pipeline kept. No barriers.
//  merge: dl staged as f16 (24KB LDS), center-out row dispatch.

#define HH    384
#define WW    384
#define NE    32
#define NK    256
#define HALF  64
#define HWSZ  (HH * WW)
#define EPSV  1e-6f
#define CAPW  160     // per-wave (32px) candidate cap
#define CAPM  192     // per-block (64px) candidate cap

typedef _Float16 half8 __attribute__((ext_vector_type(8)));
typedef _Float16 half2v __attribute__((ext_vector_type(2)));
typedef float floatx4 __attribute__((ext_vector_type(4)));

#define MFMA16(a, b, c) __builtin_amdgcn_mfma_f32_16x16x32_f16((a), (b), (c), 0, 0, 0)

__device__ __forceinline__ half2v pk_f16(float a, float b) {
    return __builtin_bit_cast(half2v, __builtin_amdgcn_cvt_pkrtz(a, b));
}

// center-out row order: heavy (central) rows dispatch first
__device__ __forceinline__ int row_order(int ri) {
    return (ri & 1) ? (191 - (ri >> 1)) : (192 + (ri >> 1));
}

// ---- ws layout (float-element offsets) ----
#define WS_DIST   0            // 4,194,304 f32 (16 MB)
#define WS_MSYM   4194304      // 65,536 f32
#define WS_W2F    4259840      // 16,384 f16 = 8,192 f32
#define WS_D      4268032      // 32,768 f16 = 16,384 f32
#define WS_CENTER 4284416      // 256 f32
#define WS_G      4284672      // 18,874,368 f16 = 9,437,184 f32

// ---------------------------------------------------------------- prep ----
__global__ void prep_kernel(const float* __restrict__ M, const float* __restrict__ W1,
                            const float* __restrict__ W2, const float* __restrict__ c,
                            const float* __restrict__ b1,
                            float* __restrict__ Msym, _Float16* __restrict__ W2f,
                            _Float16* __restrict__ D) {
    int idx = blockIdx.x * 256 + threadIdx.x;
    {   // Msym
        int i = idx >> 8, j = idx & 255;
        Msym[idx] = (i == j) ? 1.0f : 0.5f * (M[i * NK + j] + M[j * NK + i]);
    }
    if (idx < 2048) {   // W2f B-frags: lane l elem j = W2[32s+8(l>>4)+j][16nt+(l&15)]
        int l = idx & 63;
        int col = ((idx >> 8) << 4) + (l & 15);
        int kb = ((idx >> 6) & 3) * 32 + 8 * (l >> 4);
        #pragma unroll
        for (int j = 0; j < 8; ++j)
            W2f[idx * 8 + j] = (_Float16)W2[(kb + j) * 128 + col];
    }
    if (idx < 32768) {  // D[k][h] = W1^T c_k - b1
        int k = idx >> 7, h = idx & 127;
        float s = -b1[h];
        #pragma unroll 8
        for (int e = 0; e < NE; ++e) s = fmaf(c[k * NE + e], W1[e * 128 + h], s);
        D[idx] = (_Float16)s;
    }
}

// --------------------------------------------------------------- gfeat ----
__global__ __launch_bounds__(256)
void gfeat_kernel(const float* __restrict__ x, const float* __restrict__ sigma,
                  const float* __restrict__ W1, _Float16* __restrict__ G) {
    int px = blockIdx.x * 256 + threadIdx.x;
    float f[34];
    #pragma unroll
    for (int e = 0; e < NE; ++e) f[e] = x[e * HWSZ + px];
    f[32] = sigma[px];
    f[33] = sigma[HWSZ + px];
    _Float16* gp = G + (size_t)px * 128;
    #pragma unroll 1
    for (int h0 = 0; h0 < 128; h0 += 8) {
        half8 hv;
        #pragma unroll
        for (int j = 0; j < 8; ++j) {
            float z = 0.0f;
            const float* w1 = W1 + (h0 + j);
            #pragma unroll
            for (int e = 0; e < 34; ++e) z = fmaf(f[e], w1[e * 128], z);
            hv[j] = (_Float16)z;
        }
        *(half8*)(gp + h0) = hv;
    }
}

// -------------------------------------------------------------- center2 ---
__global__ __launch_bounds__(128)
void center2_kernel(const _Float16* __restrict__ G, const _Float16* __restrict__ D,
                    const float* __restrict__ W2, const float* __restrict__ b2,
                    const float* __restrict__ W3, const float* __restrict__ b3,
                    const int* __restrict__ cent, float* __restrict__ center) {
    __shared__ float h1s[128];
    __shared__ float red[2];
    int k = blockIdx.x, j = threadIdx.x;
    int cy0 = cent[2 * k], cx0 = cent[2 * k + 1];
    const _Float16* g = G + ((size_t)cy0 * WW + cx0) * 128;
    h1s[j] = fmaxf((float)g[j] - (float)D[k * 128 + j], 0.0f);
    __syncthreads();
    float acc = 0.0f;
    #pragma unroll 8
    for (int i = 0; i < 128; ++i) acc = fmaf(h1s[i], W2[i * 128 + j], acc);
    float p = fmaxf(acc + b2[j], 0.0f) * W3[j];
    #pragma unroll
    for (int m = 1; m < 64; m <<= 1) p += __shfl_xor(p, m, 64);
    if ((j & 63) == 0) red[j >> 6] = p;
    __syncthreads();
    if (j == 0) center[k] = red[0] + red[1] + b3[0];
}

// ----------------------------------------------------------------- pix ----
// Grid = 384 rows x 12 strips = 4608 one-wave blocks (64 thr, 32 px/wave).
__global__ __launch_bounds__(64, 3)
void pix_kernel(const _Float16* __restrict__ G, const _Float16* __restrict__ D,
                const _Float16* __restrict__ W2f, const int* __restrict__ cent,
                const float* __restrict__ b2, const float* __restrict__ W3,
                const float* __restrict__ b3, const float* __restrict__ center,
                float* __restrict__ dist) {
    __shared__ int   wl[CAPW];
    __shared__ float wc[CAPW];

    const int l   = threadIdx.x;
    const int lg  = l >> 4;
    const int xi  = l & 15;

    const int bid = blockIdx.x;
    const int r   = row_order(bid / 12);
    const int wx0 = (bid % 12) * 32;             // wave's 32-px x-origin

    // ---- per-wave exact candidate list (ballot-prefix, no barrier) ----
    int nw;
    {
        int base = 0;
        const int2* c2 = (const int2*)cent;
        #pragma unroll
        for (int cch = 0; cch < 4; ++cch) {
            int j = cch * 64 + l;
            int2 cc = c2[j];
            int ty = min(max(cc.x, HALF), HH - HALF) - HALF;
            int tx = min(max(cc.y, HALF), WW - HALF) - HALF;
            bool f = (r >= ty) && (r < ty + 128) &&
                     (tx <= wx0 + 31) && (tx + 127 >= wx0);
            unsigned long long m = __ballot(f);
            int pos = base + __popcll(m & ((1ull << l) - 1ull));
            if (f && pos < CAPW) {
                wl[pos] = (j << 20) | (ty << 10) | tx;
                wc[pos] = center[j];
            }
            base += __popcll(m);
        }
        nw = min(base, CAPW);
    }

    // ---- loop-invariant registers ----
    half8 B2w[8][4];
    const half8* W2f8 = (const half8*)W2f;
    #pragma unroll
    for (int n = 0; n < 8; ++n)
        #pragma unroll
        for (int s = 0; s < 4; ++s) B2w[n][s] = W2f8[(n * 4 + s) * 64 + l];

    half2v b2pk[8][2], w3pk[8][2];
    #pragma unroll
    for (int n = 0; n < 8; ++n)
        #pragma unroll
        for (int q = 0; q < 2; ++q) {
            b2pk[n][q] = half2v{(_Float16)b2[16 * n + 4 * lg + 2 * q],
                                (_Float16)b2[16 * n + 4 * lg + 2 * q + 1]};
            w3pk[n][q] = half2v{(_Float16)W3[16 * n + 4 * lg + 2 * q],
                                (_Float16)W3[16 * n + 4 * lg + 2 * q + 1]};
        }
    const float b3s = b3[0];

    // G fragments for the wave's 32 px (two 16-px groups), loaded ONCE
    half8 gA0[4], gA1[4];
    {
        const char* Gb0 = (const char*)G + ((size_t)r * WW + wx0 + xi) * 256 + lg * 16;
        const char* Gb1 = Gb0 + 16 * 256;
        #pragma unroll
        for (int s = 0; s < 4; ++s) {
            gA0[s] = *(const half8*)(Gb0 + s * 64);
            gA1[s] = *(const half8*)(Gb1 + s * 64);
        }
    }
    const half8 hz = half8{};
    const char* Dc = (const char*)D;

    auto loadD = [&](half8* dst, int cp) {
        const char* Dp = Dc + (cp >> 20) * 256 + lg * 16;
        #pragma unroll
        for (int s = 0; s < 4; ++s) dst[s] = *(const half8*)(Dp + s * 64);
    };

    auto compute = [&](const half8* Dv, int cp, float bc) {
        half8 hin0[4], hin1[4];
        #pragma unroll
        for (int s = 0; s < 4; ++s) {
            hin0[s] = __builtin_elementwise_max(gA0[s] - Dv[s], hz);
            hin1[s] = __builtin_elementwise_max(gA1[s] - Dv[s], hz);
        }
        float p0 = 0.0f, p1 = 0.0f;
        #pragma unroll
        for (int n = 0; n < 8; ++n) {
            floatx4 a0 = floatx4{0.0f, 0.0f, 0.0f, 0.0f};
            floatx4 a1 = a0;
            #pragma unroll
            for (int s = 0; s < 4; ++s) {
                a0 = MFMA16(B2w[n][s], hin0[s], a0);
                a1 = MFMA16(B2w[n][s], hin1[s], a1);
            }
            half2v h00 = __builtin_elementwise_max(pk_f16(a0[0], a0[1]) + b2pk[n][0], half2v{});
            half2v h01 = __builtin_elementwise_max(pk_f16(a0[2], a0[3]) + b2pk[n][1], half2v{});
            half2v h10 = __builtin_elementwise_max(pk_f16(a1[0], a1[1]) + b2pk[n][0], half2v{});
            half2v h11 = __builtin_elementwise_max(pk_f16(a1[2], a1[3]) + b2pk[n][1], half2v{});
            p0 = __builtin_amdgcn_fdot2(h00, w3pk[n][0], p0, false);
            p0 = __builtin_amdgcn_fdot2(h01, w3pk[n][1], p0, false);
            p1 = __builtin_amdgcn_fdot2(h10, w3pk[n][0], p1, false);
            p1 = __builtin_amdgcn_fdot2(h11, w3pk[n][1], p1, false);
        }
        p0 += __shfl_xor(p0, 16, 64);
        p0 += __shfl_xor(p0, 32, 64);
        p1 += __shfl_xor(p1, 16, 64);
        p1 += __shfl_xor(p1, 32, 64);

        if (lg < 2) {
            float pv = (lg == 0) ? p0 : p1;
            int tx = cp & 1023, ty = (cp >> 10) & 1023, j = cp >> 20;
            int px = wx0 + lg * 16 + xi;
            unsigned dx = (unsigned)(px - tx);
            if (dx < 128u) {
                float d = pv + b3s;
                float mm = fmaxf(fmaxf(d, bc), 0.0f);
                float lgv = mm + __logf(__expf(0.0f - mm) + __expf(d - mm) +
                                        __expf(bc - mm));
                dist[((size_t)j << 14) + ((r - ty) << 7) + (int)dx] = d + bc - lgv;
            }
        }
    };

    // ---- 2-stage software-pipelined candidate loop ----
    half8 Da[4], Db[4];
    int cpA = 0, cpB = 0;
    float bcA = 0.0f, bcB = 0.0f;
    if (nw > 0) { cpA = wl[0]; bcA = wc[0]; loadD(Da, cpA); }
    #pragma unroll 1
    for (int i = 0; i < nw; i += 2) {
        if (i + 1 < nw) { cpB = wl[i + 1]; bcB = wc[i + 1]; loadD(Db, cpB); }
        compute(Da, cpA, bcA);
        if (i + 1 >= nw) break;
        if (i + 2 < nw) { cpA = wl[i + 2]; bcA = wc[i + 2]; loadD(Da, cpA); }
        compute(Db, cpB, bcB);
    }
}

// --------------------------------------------------------------- merge ----
// Grid = 384 rows x 6 xtiles = 2304 blocks of 256. dl staged as f16 (24KB).
__global__ __launch_bounds__(256)
void merge_kernel(const float* __restrict__ dist, const int* __restrict__ cent,
                  const float* __restrict__ Msym, float* __restrict__ out) {
    __shared__ _Float16 dl[CAPM][64];    // 24 KB
    __shared__ int   sjw[CAPM];
    __shared__ int2  mpk[4][CAPM];       // 6 KB {m bits, tx}
    __shared__ int   scnt;

    const int tid = threadIdx.x;
    const int l   = tid & 63;
    const int wv  = tid >> 6;
    const int r   = row_order(blockIdx.x / 6);
    const int xt  = blockIdx.x % 6;
    const int px  = xt * 64 + l;

    // ---- block candidate list (wave 0, ballot-prefix) ----
    if (wv == 0) {
        int base = 0;
        const int2* c2 = (const int2*)cent;
        #pragma unroll
        for (int cch = 0; cch < 4; ++cch) {
            int j = cch * 64 + l;
            int2 cc = c2[j];
            int ty = min(max(cc.x, HALF), HH - HALF) - HALF;
            int tx = min(max(cc.y, HALF), WW - HALF) - HALF;
            bool f = (r >= ty) && (r < ty + 128) &&
                     (tx <= xt * 64 + 63) && (tx + 127 >= xt * 64);
            unsigned long long m = __ballot(f);
            int pos = base + __popcll(m & ((1ull << l) - 1ull));
            if (f && pos < CAPM) sjw[pos] = (j << 20) | (ty << 10) | tx;
            base += __popcll(m);
        }
        if (l == 0) scnt = min(base, CAPM);
    }
    __syncthreads();
    const int nc = scnt;

    // ---- stage dl[j][px]: one coalesced dist row-segment per candidate ----
    #pragma unroll 1
    for (int j = wv; j < nc; j += 4) {
        int cp = sjw[j];
        int tx = cp & 1023, ty = (cp >> 10) & 1023, jj = cp >> 20;
        unsigned dx = (unsigned)(px - tx);
        float v = 0.0f;
        if (dx < 128u) v = dist[((size_t)jj << 14) + ((r - ty) << 7) + (int)dx];
        dl[j][l] = (_Float16)v;
    }
    __syncthreads();

    // ---- t-loop: one output window per wave-iteration ----
    #pragma unroll 1
    for (int t = wv; t < nc; t += 4) {
        int cpt = sjw[t];
        int kt = cpt >> 20;
        const float* mrow = Msym + kt * NK;
        #pragma unroll
        for (int cch = 0; cch < 3; ++cch) {      // compact (m, tx) pairs
            int j2 = cch * 64 + l;
            if (j2 < nc) {
                int cj = sjw[j2];
                mpk[wv][j2] = int2{__builtin_bit_cast(int, mrow[cj >> 20]),
                                   cj & 1023};
            }
        }
        float num = 0.0f, den = 0.0f;
        #pragma unroll 4
        for (int j = 0; j < nc; ++j) {
            int2 mp = mpk[wv][j];
            float m = __builtin_bit_cast(float, mp.x);
            num = fmaf(m, (float)dl[j][l], num); // dl = 0 where uncovered
            unsigned dxj = (unsigned)(px - mp.y);
            den += (dxj < 128u) ? m : 0.0f;
        }
        unsigned dxk = (unsigned)(px - (cpt & 1023));
        if (dxk < 128u)
            out[((size_t)kt << 14) + ((r - ((cpt >> 10) & 1023)) << 7) + (int)dxk] =
                num / fmaxf(den, EPSV);
    }
}

// -------------------------------------------------------------- launch ----
extern "C" void kernel_launch(void* const* d_in, const int* in_sizes, int n_in,
                              void* d_out, int out_size, void* d_ws, size_t ws_size,
                              hipStream_t stream) {
    const float* x     = (const float*)d_in[0];
    const float* sigma = (const float*)d_in[1];
    const float* c     = (const float*)d_in[2];
    const int*   cent  = (const int*)d_in[3];
    const float* M     = (const float*)d_in[4];
    const float* W1    = (const float*)d_in[5];
    const float* b1    = (const float*)d_in[6];
    const float* W2    = (const float*)d_in[7];
    const float* b2    = (const float*)d_in[8];
    const float* W3    = (const float*)d_in[9];
    const float* b3    = (const float*)d_in[10];
    float* out = (float*)d_out;

    float* ws       = (float*)d_ws;
    float* dist     = ws + WS_DIST;
    float* Msym     = ws + WS_MSYM;
    _Float16* W2f   = (_Float16*)(ws + WS_W2F);
    _Float16* D     = (_Float16*)(ws + WS_D);
    float* center   = ws + WS_CENTER;
    _Float16* G     = (_Float16*)(ws + WS_G);

    prep_kernel<<<256, 256, 0, stream>>>(M, W1, W2, c, b1, Msym, W2f, D);
    gfeat_kernel<<<576, 256, 0, stream>>>(x, sigma, W1, G);
    center2_kernel<<<256, 128, 0, stream>>>(G, D, W2, b2, W3, b3, cent, center);
    pix_kernel<<<4608, 64, 0, stream>>>(G, D, W2f, cent, b2, W3, b3, center, dist);
    merge_kernel<<<2304, 256, 0, stream>>>(dist, cent, Msym, out);
}

// Round 11
// 406.467 us; speedup vs baseline: 2.0636x; 2.0636x over previous
//
#include <hip/hip_runtime.h>
#include <hip/hip_bf16.h>

// InstanSeg v10: v9 post-mortem — __launch_bounds__(64,3) spilled B2w
// (VGPR 84, FETCH 2GB of scratch). Revert to v8's 256-thr no-cap codegen
// (152 VGPR, no spill) but keep v9's wave-level work items + center-out
// order: item = bid*4 + wv -> (row, 32px strip). Merge kept from v9.

#define HH    384
#define WW    384
#define NE    32
#define NK    256
#define HALF  64
#define HWSZ  (HH * WW)
#define EPSV  1e-6f
#define CAPW  160     // per-wave (32px) candidate cap
#define CAPM  192     // per-block (64px) candidate cap

typedef _Float16 half8 __attribute__((ext_vector_type(8)));
typedef _Float16 half2v __attribute__((ext_vector_type(2)));
typedef float floatx4 __attribute__((ext_vector_type(4)));

#define MFMA16(a, b, c) __builtin_amdgcn_mfma_f32_16x16x32_f16((a), (b), (c), 0, 0, 0)

__device__ __forceinline__ half2v pk_f16(float a, float b) {
    return __builtin_bit_cast(half2v, __builtin_amdgcn_cvt_pkrtz(a, b));
}

// center-out row order: heavy (central) rows dispatch first
__device__ __forceinline__ int row_order(int ri) {
    return (ri & 1) ? (191 - (ri >> 1)) : (192 + (ri >> 1));
}

// ---- ws layout (float-element offsets) ----
#define WS_DIST   0            // 4,194,304 f32 (16 MB)
#define WS_MSYM   4194304      // 65,536 f32
#define WS_W2F    4259840      // 16,384 f16 = 8,192 f32
#define WS_D      4268032      // 32,768 f16 = 16,384 f32
#define WS_CENTER 4284416      // 256 f32
#define WS_G      4284672      // 18,874,368 f16 = 9,437,184 f32

// ---------------------------------------------------------------- prep ----
__global__ void prep_kernel(const float* __restrict__ M, const float* __restrict__ W1,
                            const float* __restrict__ W2, const float* __restrict__ c,
                            const float* __restrict__ b1,
                            float* __restrict__ Msym, _Float16* __restrict__ W2f,
                            _Float16* __restrict__ D) {
    int idx = blockIdx.x * 256 + threadIdx.x;
    {   // Msym
        int i = idx >> 8, j = idx & 255;
        Msym[idx] = (i == j) ? 1.0f : 0.5f * (M[i * NK + j] + M[j * NK + i]);
    }
    if (idx < 2048) {   // W2f B-frags: lane l elem j = W2[32s+8(l>>4)+j][16nt+(l&15)]
        int l = idx & 63;
        int col = ((idx >> 8) << 4) + (l & 15);
        int kb = ((idx >> 6) & 3) * 32 + 8 * (l >> 4);
        #pragma unroll
        for (int j = 0; j < 8; ++j)
            W2f[idx * 8 + j] = (_Float16)W2[(kb + j) * 128 + col];
    }
    if (idx < 32768) {  // D[k][h] = W1^T c_k - b1
        int k = idx >> 7, h = idx & 127;
        float s = -b1[h];
        #pragma unroll 8
        for (int e = 0; e < NE; ++e) s = fmaf(c[k * NE + e], W1[e * 128 + h], s);
        D[idx] = (_Float16)s;
    }
}

// --------------------------------------------------------------- gfeat ----
__global__ __launch_bounds__(256)
void gfeat_kernel(const float* __restrict__ x, const float* __restrict__ sigma,
                  const float* __restrict__ W1, _Float16* __restrict__ G) {
    int px = blockIdx.x * 256 + threadIdx.x;
    float f[34];
    #pragma unroll
    for (int e = 0; e < NE; ++e) f[e] = x[e * HWSZ + px];
    f[32] = sigma[px];
    f[33] = sigma[HWSZ + px];
    _Float16* gp = G + (size_t)px * 128;
    #pragma unroll 1
    for (int h0 = 0; h0 < 128; h0 += 8) {
        half8 hv;
        #pragma unroll
        for (int j = 0; j < 8; ++j) {
            float z = 0.0f;
            const float* w1 = W1 + (h0 + j);
            #pragma unroll
            for (int e = 0; e < 34; ++e) z = fmaf(f[e], w1[e * 128], z);
            hv[j] = (_Float16)z;
        }
        *(half8*)(gp + h0) = hv;
    }
}

// -------------------------------------------------------------- center2 ---
__global__ __launch_bounds__(128)
void center2_kernel(const _Float16* __restrict__ G, const _Float16* __restrict__ D,
                    const float* __restrict__ W2, const float* __restrict__ b2,
                    const float* __restrict__ W3, const float* __restrict__ b3,
                    const int* __restrict__ cent, float* __restrict__ center) {
    __shared__ float h1s[128];
    __shared__ float red[2];
    int k = blockIdx.x, j = threadIdx.x;
    int cy0 = cent[2 * k], cx0 = cent[2 * k + 1];
    const _Float16* g = G + ((size_t)cy0 * WW + cx0) * 128;
    h1s[j] = fmaxf((float)g[j] - (float)D[k * 128 + j], 0.0f);
    __syncthreads();
    float acc = 0.0f;
    #pragma unroll 8
    for (int i = 0; i < 128; ++i) acc = fmaf(h1s[i], W2[i * 128 + j], acc);
    float p = fmaxf(acc + b2[j], 0.0f) * W3[j];
    #pragma unroll
    for (int m = 1; m < 64; m <<= 1) p += __shfl_xor(p, m, 64);
    if ((j & 63) == 0) red[j >> 6] = p;
    __syncthreads();
    if (j == 0) center[k] = red[0] + red[1] + b3[0];
}

// ----------------------------------------------------------------- pix ----
// Grid = 1152 blocks x 256 thr; wave wv owns item = bid*4+wv ->
// (row = row_order(item/12), 32-px strip = (item%12)*32). No block barrier.
__global__ __launch_bounds__(256)
void pix_kernel(const _Float16* __restrict__ G, const _Float16* __restrict__ D,
                const _Float16* __restrict__ W2f, const int* __restrict__ cent,
                const float* __restrict__ b2, const float* __restrict__ W3,
                const float* __restrict__ b3, const float* __restrict__ center,
                float* __restrict__ dist) {
    __shared__ int   wl[4][CAPW];
    __shared__ float wc[4][CAPW];

    const int tid = threadIdx.x;
    const int l   = tid & 63;
    const int wv  = tid >> 6;
    const int lg  = l >> 4;
    const int xi  = l & 15;

    const int item = blockIdx.x * 4 + wv;
    const int r    = row_order(item / 12);
    const int wx0  = (item % 12) * 32;           // wave's 32-px x-origin

    // ---- per-wave exact candidate list (ballot-prefix, no barrier) ----
    int nw;
    {
        int base = 0;
        const int2* c2 = (const int2*)cent;
        #pragma unroll
        for (int cch = 0; cch < 4; ++cch) {
            int j = cch * 64 + l;
            int2 cc = c2[j];
            int ty = min(max(cc.x, HALF), HH - HALF) - HALF;
            int tx = min(max(cc.y, HALF), WW - HALF) - HALF;
            bool f = (r >= ty) && (r < ty + 128) &&
                     (tx <= wx0 + 31) && (tx + 127 >= wx0);
            unsigned long long m = __ballot(f);
            int pos = base + __popcll(m & ((1ull << l) - 1ull));
            if (f && pos < CAPW) {
                wl[wv][pos] = (j << 20) | (ty << 10) | tx;
                wc[wv][pos] = center[j];
            }
            base += __popcll(m);
        }
        nw = min(base, CAPW);
    }

    // ---- loop-invariant registers ----
    half8 B2w[8][4];
    const half8* W2f8 = (const half8*)W2f;
    #pragma unroll
    for (int n = 0; n < 8; ++n)
        #pragma unroll
        for (int s = 0; s < 4; ++s) B2w[n][s] = W2f8[(n * 4 + s) * 64 + l];

    float b2v[8][4];
    half2v w3pk[8][2];
    #pragma unroll
    for (int n = 0; n < 8; ++n) {
        #pragma unroll
        for (int q = 0; q < 4; ++q) b2v[n][q] = b2[16 * n + 4 * lg + q];
        #pragma unroll
        for (int q = 0; q < 2; ++q)
            w3pk[n][q] = half2v{(_Float16)W3[16 * n + 4 * lg + 2 * q],
                                (_Float16)W3[16 * n + 4 * lg + 2 * q + 1]};
    }
    const float b3s = b3[0];

    // G fragments for the wave's 32 px (two 16-px groups), loaded ONCE
    half8 gA0[4], gA1[4];
    {
        const char* Gb0 = (const char*)G + ((size_t)r * WW + wx0 + xi) * 256 + lg * 16;
        const char* Gb1 = Gb0 + 16 * 256;
        #pragma unroll
        for (int s = 0; s < 4; ++s) {
            gA0[s] = *(const half8*)(Gb0 + s * 64);
            gA1[s] = *(const half8*)(Gb1 + s * 64);
        }
    }
    const half8 hz = half8{};
    const char* Dc = (const char*)D;

    auto loadD = [&](half8* dst, int cp) {
        const char* Dp = Dc + (cp >> 20) * 256 + lg * 16;
        #pragma unroll
        for (int s = 0; s < 4; ++s) dst[s] = *(const half8*)(Dp + s * 64);
    };

    auto compute = [&](const half8* Dv, int cp, float bc) {
        half8 hin0[4], hin1[4];
        #pragma unroll
        for (int s = 0; s < 4; ++s) {
            hin0[s] = __builtin_elementwise_max(gA0[s] - Dv[s], hz);
            hin1[s] = __builtin_elementwise_max(gA1[s] - Dv[s], hz);
        }
        float p0 = 0.0f, p1 = 0.0f;
        #pragma unroll
        for (int n = 0; n < 8; ++n) {
            floatx4 a0 = floatx4{b2v[n][0], b2v[n][1], b2v[n][2], b2v[n][3]};
            floatx4 a1 = a0;
            #pragma unroll
            for (int s = 0; s < 4; ++s) {
                a0 = MFMA16(B2w[n][s], hin0[s], a0);
                a1 = MFMA16(B2w[n][s], hin1[s], a1);
            }
            half2v h00 = __builtin_elementwise_max(pk_f16(a0[0], a0[1]), half2v{});
            half2v h01 = __builtin_elementwise_max(pk_f16(a0[2], a0[3]), half2v{});
            half2v h10 = __builtin_elementwise_max(pk_f16(a1[0], a1[1]), half2v{});
            half2v h11 = __builtin_elementwise_max(pk_f16(a1[2], a1[3]), half2v{});
            p0 = __builtin_amdgcn_fdot2(h00, w3pk[n][0], p0, false);
            p0 = __builtin_amdgcn_fdot2(h01, w3pk[n][1], p0, false);
            p1 = __builtin_amdgcn_fdot2(h10, w3pk[n][0], p1, false);
            p1 = __builtin_amdgcn_fdot2(h11, w3pk[n][1], p1, false);
        }
        p0 += __shfl_xor(p0, 16, 64);
        p0 += __shfl_xor(p0, 32, 64);
        p1 += __shfl_xor(p1, 16, 64);
        p1 += __shfl_xor(p1, 32, 64);

        if (lg < 2) {
            float pv = (lg == 0) ? p0 : p1;
            int tx = cp & 1023, ty = (cp >> 10) & 1023, j = cp >> 20;
            int px = wx0 + lg * 16 + xi;
            unsigned dx = (unsigned)(px - tx);
            if (dx < 128u) {
                float d = pv + b3s;
                float mm = fmaxf(fmaxf(d, bc), 0.0f);
                float lgv = mm + __logf(__expf(0.0f - mm) + __expf(d - mm) +
                                        __expf(bc - mm));
                dist[((size_t)j << 14) + ((r - ty) << 7) + (int)dx] = d + bc - lgv;
            }
        }
    };

    // ---- 2-stage software-pipelined candidate loop ----
    half8 Da[4], Db[4];
    int cpA = 0, cpB = 0;
    float bcA = 0.0f, bcB = 0.0f;
    if (nw > 0) { cpA = wl[wv][0]; bcA = wc[wv][0]; loadD(Da, cpA); }
    #pragma unroll 1
    for (int i = 0; i < nw; i += 2) {
        if (i + 1 < nw) { cpB = wl[wv][i + 1]; bcB = wc[wv][i + 1]; loadD(Db, cpB); }
        compute(Da, cpA, bcA);
        if (i + 1 >= nw) break;
        if (i + 2 < nw) { cpA = wl[wv][i + 2]; bcA = wc[wv][i + 2]; loadD(Da, cpA); }
        compute(Db, cpB, bcB);
    }
}

// --------------------------------------------------------------- merge ----
// Grid = 384 rows x 6 xtiles = 2304 blocks of 256. dl staged as f16 (24KB).
__global__ __launch_bounds__(256)
void merge_kernel(const float* __restrict__ dist, const int* __restrict__ cent,
                  const float* __restrict__ Msym, float* __restrict__ out) {
    __shared__ _Float16 dl[CAPM][64];    // 24 KB
    __shared__ int   sjw[CAPM];
    __shared__ int2  mpk[4][CAPM];       // 6 KB {m bits, tx}
    __shared__ int   scnt;

    const int tid = threadIdx.x;
    const int l   = tid & 63;
    const int wv  = tid >> 6;
    const int r   = row_order(blockIdx.x / 6);
    const int xt  = blockIdx.x % 6;
    const int px  = xt * 64 + l;

    // ---- block candidate list (wave 0, ballot-prefix) ----
    if (wv == 0) {
        int base = 0;
        const int2* c2 = (const int2*)cent;
        #pragma unroll
        for (int cch = 0; cch < 4; ++cch) {
            int j = cch * 64 + l;
            int2 cc = c2[j];
            int ty = min(max(cc.x, HALF), HH - HALF) - HALF;
            int tx = min(max(cc.y, HALF), WW - HALF) - HALF;
            bool f = (r >= ty) && (r < ty + 128) &&
                     (tx <= xt * 64 + 63) && (tx + 127 >= xt * 64);
            unsigned long long m = __ballot(f);
            int pos = base + __popcll(m & ((1ull << l) - 1ull));
            if (f && pos < CAPM) sjw[pos] = (j << 20) | (ty << 10) | tx;
            base += __popcll(m);
        }
        if (l == 0) scnt = min(base, CAPM);
    }
    __syncthreads();
    const int nc = scnt;

    // ---- stage dl[j][px]: one coalesced dist row-segment per candidate ----
    #pragma unroll 1
    for (int j = wv; j < nc; j += 4) {
        int cp = sjw[j];
        int tx = cp & 1023, ty = (cp >> 10) & 1023, jj = cp >> 20;
        unsigned dx = (unsigned)(px - tx);
        float v = 0.0f;
        if (dx < 128u) v = dist[((size_t)jj << 14) + ((r - ty) << 7) + (int)dx];
        dl[j][l] = (_Float16)v;
    }
    __syncthreads();

    // ---- t-loop: one output window per wave-iteration ----
    #pragma unroll 1
    for (int t = wv; t < nc; t += 4) {
        int cpt = sjw[t];
        int kt = cpt >> 20;
        const float* mrow = Msym + kt * NK;
        #pragma unroll
        for (int cch = 0; cch < 3; ++cch) {      // compact (m, tx) pairs
            int j2 = cch * 64 + l;
            if (j2 < nc) {
                int cj = sjw[j2];
                mpk[wv][j2] = int2{__builtin_bit_cast(int, mrow[cj >> 20]),
                                   cj & 1023};
            }
        }
        float num = 0.0f, den = 0.0f;
        #pragma unroll 4
        for (int j = 0; j < nc; ++j) {
            int2 mp = mpk[wv][j];
            float m = __builtin_bit_cast(float, mp.x);
            num = fmaf(m, (float)dl[j][l], num); // dl = 0 where uncovered
            unsigned dxj = (unsigned)(px - mp.y);
            den += (dxj < 128u) ? m : 0.0f;
        }
        unsigned dxk = (unsigned)(px - (cpt & 1023));
        if (dxk < 128u)
            out[((size_t)kt << 14) + ((r - ((cpt >> 10) & 1023)) << 7) + (int)dxk] =
                num / fmaxf(den, EPSV);
    }
}

// -------------------------------------------------------------- launch ----
extern "C" void kernel_launch(void* const* d_in, const int* in_sizes, int n_in,
                              void* d_out, int out_size, void* d_ws, size_t ws_size,
                              hipStream_t stream) {
    const float* x     = (const float*)d_in[0];
    const float* sigma = (const float*)d_in[1];
    const float* c     = (const float*)d_in[2];
    const int*   cent  = (const int*)d_in[3];
    const float* M     = (const float*)d_in[4];
    const float* W1    = (const float*)d_in[5];
    const float* b1    = (const float*)d_in[6];
    const float* W2    = (const float*)d_in[7];
    const float* b2    = (const float*)d_in[8];
    const float* W3    = (const float*)d_in[9];
    const float* b3    = (const float*)d_in[10];
    float* out = (float*)d_out;

    float* ws       = (float*)d_ws;
    float* dist     = ws + WS_DIST;
    float* Msym     = ws + WS_MSYM;
    _Float16* W2f   = (_Float16*)(ws + WS_W2F);
    _Float16* D     = (_Float16*)(ws + WS_D);
    float* center   = ws + WS_CENTER;
    _Float16* G     = (_Float16*)(ws + WS_G);

    prep_kernel<<<256, 256, 0, stream>>>(M, W1, W2, c, b1, Msym, W2f, D);
    gfeat_kernel<<<576, 256, 0, stream>>>(x, sigma, W1, G);
    center2_kernel<<<256, 128, 0, stream>>>(G, D, W2, b2, W3, b3, cent, center);
    pix_kernel<<<1152, 256, 0, stream>>>(G, D, W2f, cent, b2, W3, b3, center, dist);
    merge_kernel<<<2304, 256, 0, stream>>>(dist, cent, Msym, out);
}

// Round 12
// 352.596 us; speedup vs baseline: 2.3789x; 1.1528x over previous
//
#include <hip/hip_runtime.h>
#include <hip/hip_bf16.h>

// InstanSeg v11: v10 + persistent-wave work stealing for pix.
// v10 post-mortem: occupancy 8.5% — grid 4.5 blocks/CU, no refill behind
// 3 resident -> latency-exposed. Now: 768 blocks (exactly 3/CU resident),
// each wave steals (row, 32px-strip) items from a global counter,
// center-out order so heavy items go first. Counter zeroed in prep.

#define HH    384
#define WW    384
#define NE    32
#define NK    256
#define HALF  64
#define HWSZ  (HH * WW)
#define EPSV  1e-6f
#define CAPW  160     // per-wave (32px) candidate cap
#define CAPM  192     // per-block (64px) candidate cap
#define NITEMS 4608   // 384 rows x 12 strips

typedef _Float16 half8 __attribute__((ext_vector_type(8)));
typedef _Float16 half2v __attribute__((ext_vector_type(2)));
typedef float floatx4 __attribute__((ext_vector_type(4)));

#define MFMA16(a, b, c) __builtin_amdgcn_mfma_f32_16x16x32_f16((a), (b), (c), 0, 0, 0)

__device__ __forceinline__ half2v pk_f16(float a, float b) {
    return __builtin_bit_cast(half2v, __builtin_amdgcn_cvt_pkrtz(a, b));
}

// center-out row order: heavy (central) rows dispatch first
__device__ __forceinline__ int row_order(int ri) {
    return (ri & 1) ? (191 - (ri >> 1)) : (192 + (ri >> 1));
}

// ---- ws layout (float-element offsets) ----
#define WS_DIST   0            // 4,194,304 f32 (16 MB)
#define WS_MSYM   4194304      // 65,536 f32
#define WS_W2F    4259840      // 16,384 f16 = 8,192 f32
#define WS_D      4268032      // 32,768 f16 = 16,384 f32
#define WS_CENTER 4284416      // 256 f32
#define WS_CTR    4284672      // 1 int (steal counter)
#define WS_G      4284928      // 18,874,368 f16 = 9,437,184 f32

// ---------------------------------------------------------------- prep ----
__global__ void prep_kernel(const float* __restrict__ M, const float* __restrict__ W1,
                            const float* __restrict__ W2, const float* __restrict__ c,
                            const float* __restrict__ b1,
                            float* __restrict__ Msym, _Float16* __restrict__ W2f,
                            _Float16* __restrict__ D, int* __restrict__ gctr) {
    int idx = blockIdx.x * 256 + threadIdx.x;
    if (idx == 0) *gctr = 0;
    {   // Msym
        int i = idx >> 8, j = idx & 255;
        Msym[idx] = (i == j) ? 1.0f : 0.5f * (M[i * NK + j] + M[j * NK + i]);
    }
    if (idx < 2048) {   // W2f B-frags: lane l elem j = W2[32s+8(l>>4)+j][16nt+(l&15)]
        int l = idx & 63;
        int col = ((idx >> 8) << 4) + (l & 15);
        int kb = ((idx >> 6) & 3) * 32 + 8 * (l >> 4);
        #pragma unroll
        for (int j = 0; j < 8; ++j)
            W2f[idx * 8 + j] = (_Float16)W2[(kb + j) * 128 + col];
    }
    if (idx < 32768) {  // D[k][h] = W1^T c_k - b1
        int k = idx >> 7, h = idx & 127;
        float s = -b1[h];
        #pragma unroll 8
        for (int e = 0; e < NE; ++e) s = fmaf(c[k * NE + e], W1[e * 128 + h], s);
        D[idx] = (_Float16)s;
    }
}

// --------------------------------------------------------------- gfeat ----
__global__ __launch_bounds__(256)
void gfeat_kernel(const float* __restrict__ x, const float* __restrict__ sigma,
                  const float* __restrict__ W1, _Float16* __restrict__ G) {
    int px = blockIdx.x * 256 + threadIdx.x;
    float f[34];
    #pragma unroll
    for (int e = 0; e < NE; ++e) f[e] = x[e * HWSZ + px];
    f[32] = sigma[px];
    f[33] = sigma[HWSZ + px];
    _Float16* gp = G + (size_t)px * 128;
    #pragma unroll 1
    for (int h0 = 0; h0 < 128; h0 += 8) {
        half8 hv;
        #pragma unroll
        for (int j = 0; j < 8; ++j) {
            float z = 0.0f;
            const float* w1 = W1 + (h0 + j);
            #pragma unroll
            for (int e = 0; e < 34; ++e) z = fmaf(f[e], w1[e * 128], z);
            hv[j] = (_Float16)z;
        }
        *(half8*)(gp + h0) = hv;
    }
}

// -------------------------------------------------------------- center2 ---
__global__ __launch_bounds__(128)
void center2_kernel(const _Float16* __restrict__ G, const _Float16* __restrict__ D,
                    const float* __restrict__ W2, const float* __restrict__ b2,
                    const float* __restrict__ W3, const float* __restrict__ b3,
                    const int* __restrict__ cent, float* __restrict__ center) {
    __shared__ float h1s[128];
    __shared__ float red[2];
    int k = blockIdx.x, j = threadIdx.x;
    int cy0 = cent[2 * k], cx0 = cent[2 * k + 1];
    const _Float16* g = G + ((size_t)cy0 * WW + cx0) * 128;
    h1s[j] = fmaxf((float)g[j] - (float)D[k * 128 + j], 0.0f);
    __syncthreads();
    float acc = 0.0f;
    #pragma unroll 8
    for (int i = 0; i < 128; ++i) acc = fmaf(h1s[i], W2[i * 128 + j], acc);
    float p = fmaxf(acc + b2[j], 0.0f) * W3[j];
    #pragma unroll
    for (int m = 1; m < 64; m <<= 1) p += __shfl_xor(p, m, 64);
    if ((j & 63) == 0) red[j >> 6] = p;
    __syncthreads();
    if (j == 0) center[k] = red[0] + red[1] + b3[0];
}

// ----------------------------------------------------------------- pix ----
// 768 persistent blocks x 256 thr; each wave steals items (row, 32px strip).
__global__ __launch_bounds__(256)
void pix_kernel(const _Float16* __restrict__ G, const _Float16* __restrict__ D,
                const _Float16* __restrict__ W2f, const int* __restrict__ cent,
                const float* __restrict__ b2, const float* __restrict__ W3,
                const float* __restrict__ b3, const float* __restrict__ center,
                int* __restrict__ gctr, float* __restrict__ dist) {
    __shared__ int   wl[4][CAPW];
    __shared__ float wc[4][CAPW];

    const int tid = threadIdx.x;
    const int l   = tid & 63;
    const int wv  = tid >> 6;
    const int lg  = l >> 4;
    const int xi  = l & 15;

    // ---- loop-invariant registers ----
    half8 B2w[8][4];
    const half8* W2f8 = (const half8*)W2f;
    #pragma unroll
    for (int n = 0; n < 8; ++n)
        #pragma unroll
        for (int s = 0; s < 4; ++s) B2w[n][s] = W2f8[(n * 4 + s) * 64 + l];

    float b2v[8][4];
    half2v w3pk[8][2];
    #pragma unroll
    for (int n = 0; n < 8; ++n) {
        #pragma unroll
        for (int q = 0; q < 4; ++q) b2v[n][q] = b2[16 * n + 4 * lg + q];
        #pragma unroll
        for (int q = 0; q < 2; ++q)
            w3pk[n][q] = half2v{(_Float16)W3[16 * n + 4 * lg + 2 * q],
                                (_Float16)W3[16 * n + 4 * lg + 2 * q + 1]};
    }
    const float b3s = b3[0];
    const half8 hz = half8{};
    const char* Dc = (const char*)D;
    const int2* c2 = (const int2*)cent;

    // ---- persistent steal loop ----
    #pragma unroll 1
    for (;;) {
        int pos = 0;
        if (l == 0) pos = atomicAdd(gctr, 1);
        pos = __shfl(pos, 0, 64);
        if (pos >= NITEMS) break;

        const int r   = row_order(pos / 12);
        const int wx0 = (pos % 12) * 32;

        // per-wave exact candidate list (ballot-prefix, no barrier)
        int nw;
        {
            int base = 0;
            #pragma unroll
            for (int cch = 0; cch < 4; ++cch) {
                int j = cch * 64 + l;
                int2 cc = c2[j];
                int ty = min(max(cc.x, HALF), HH - HALF) - HALF;
                int tx = min(max(cc.y, HALF), WW - HALF) - HALF;
                bool f = (r >= ty) && (r < ty + 128) &&
                         (tx <= wx0 + 31) && (tx + 127 >= wx0);
                unsigned long long m = __ballot(f);
                int p2 = base + __popcll(m & ((1ull << l) - 1ull));
                if (f && p2 < CAPW) {
                    wl[wv][p2] = (j << 20) | (ty << 10) | tx;
                    wc[wv][p2] = center[j];
                }
                base += __popcll(m);
            }
            nw = min(base, CAPW);
        }

        // G fragments for this item's 32 px (two 16-px groups)
        half8 gA0[4], gA1[4];
        {
            const char* Gb0 = (const char*)G + ((size_t)r * WW + wx0 + xi) * 256 + lg * 16;
            const char* Gb1 = Gb0 + 16 * 256;
            #pragma unroll
            for (int s = 0; s < 4; ++s) {
                gA0[s] = *(const half8*)(Gb0 + s * 64);
                gA1[s] = *(const half8*)(Gb1 + s * 64);
            }
        }

        auto loadD = [&](half8* dst, int cp) {
            const char* Dp = Dc + (cp >> 20) * 256 + lg * 16;
            #pragma unroll
            for (int s = 0; s < 4; ++s) dst[s] = *(const half8*)(Dp + s * 64);
        };

        auto compute = [&](const half8* Dv, int cp, float bc) {
            half8 hin0[4], hin1[4];
            #pragma unroll
            for (int s = 0; s < 4; ++s) {
                hin0[s] = __builtin_elementwise_max(gA0[s] - Dv[s], hz);
                hin1[s] = __builtin_elementwise_max(gA1[s] - Dv[s], hz);
            }
            float p0 = 0.0f, p1 = 0.0f;
            #pragma unroll
            for (int n = 0; n < 8; ++n) {
                floatx4 a0 = floatx4{b2v[n][0], b2v[n][1], b2v[n][2], b2v[n][3]};
                floatx4 a1 = a0;
                #pragma unroll
                for (int s = 0; s < 4; ++s) {
                    a0 = MFMA16(B2w[n][s], hin0[s], a0);
                    a1 = MFMA16(B2w[n][s], hin1[s], a1);
                }
                half2v h00 = __builtin_elementwise_max(pk_f16(a0[0], a0[1]), half2v{});
                half2v h01 = __builtin_elementwise_max(pk_f16(a0[2], a0[3]), half2v{});
                half2v h10 = __builtin_elementwise_max(pk_f16(a1[0], a1[1]), half2v{});
                half2v h11 = __builtin_elementwise_max(pk_f16(a1[2], a1[3]), half2v{});
                p0 = __builtin_amdgcn_fdot2(h00, w3pk[n][0], p0, false);
                p0 = __builtin_amdgcn_fdot2(h01, w3pk[n][1], p0, false);
                p1 = __builtin_amdgcn_fdot2(h10, w3pk[n][0], p1, false);
                p1 = __builtin_amdgcn_fdot2(h11, w3pk[n][1], p1, false);
            }
            p0 += __shfl_xor(p0, 16, 64);
            p0 += __shfl_xor(p0, 32, 64);
            p1 += __shfl_xor(p1, 16, 64);
            p1 += __shfl_xor(p1, 32, 64);

            if (lg < 2) {
                float pv = (lg == 0) ? p0 : p1;
                int tx = cp & 1023, ty = (cp >> 10) & 1023, j = cp >> 20;
                int px = wx0 + lg * 16 + xi;
                unsigned dx = (unsigned)(px - tx);
                if (dx < 128u) {
                    float d = pv + b3s;
                    float mm = fmaxf(fmaxf(d, bc), 0.0f);
                    float lgv = mm + __logf(__expf(0.0f - mm) + __expf(d - mm) +
                                            __expf(bc - mm));
                    dist[((size_t)j << 14) + ((r - ty) << 7) + (int)dx] = d + bc - lgv;
                }
            }
        };

        // 2-stage software-pipelined candidate loop
        half8 Da[4], Db[4];
        int cpA = 0, cpB = 0;
        float bcA = 0.0f, bcB = 0.0f;
        if (nw > 0) { cpA = wl[wv][0]; bcA = wc[wv][0]; loadD(Da, cpA); }
        #pragma unroll 1
        for (int i = 0; i < nw; i += 2) {
            if (i + 1 < nw) { cpB = wl[wv][i + 1]; bcB = wc[wv][i + 1]; loadD(Db, cpB); }
            compute(Da, cpA, bcA);
            if (i + 1 >= nw) break;
            if (i + 2 < nw) { cpA = wl[wv][i + 2]; bcA = wc[wv][i + 2]; loadD(Da, cpA); }
            compute(Db, cpB, bcB);
        }
    }
}

// --------------------------------------------------------------- merge ----
// Grid = 384 rows x 6 xtiles = 2304 blocks of 256. dl staged as f16 (24KB).
__global__ __launch_bounds__(256)
void merge_kernel(const float* __restrict__ dist, const int* __restrict__ cent,
                  const float* __restrict__ Msym, float* __restrict__ out) {
    __shared__ _Float16 dl[CAPM][64];    // 24 KB
    __shared__ int   sjw[CAPM];
    __shared__ int2  mpk[4][CAPM];       // 6 KB {m bits, tx}
    __shared__ int   scnt;

    const int tid = threadIdx.x;
    const int l   = tid & 63;
    const int wv  = tid >> 6;
    const int r   = row_order(blockIdx.x / 6);
    const int xt  = blockIdx.x % 6;
    const int px  = xt * 64 + l;

    // ---- block candidate list (wave 0, ballot-prefix) ----
    if (wv == 0) {
        int base = 0;
        const int2* c2 = (const int2*)cent;
        #pragma unroll
        for (int cch = 0; cch < 4; ++cch) {
            int j = cch * 64 + l;
            int2 cc = c2[j];
            int ty = min(max(cc.x, HALF), HH - HALF) - HALF;
            int tx = min(max(cc.y, HALF), WW - HALF) - HALF;
            bool f = (r >= ty) && (r < ty + 128) &&
                     (tx <= xt * 64 + 63) && (tx + 127 >= xt * 64);
            unsigned long long m = __ballot(f);
            int pos = base + __popcll(m & ((1ull << l) - 1ull));
            if (f && pos < CAPM) sjw[pos] = (j << 20) | (ty << 10) | tx;
            base += __popcll(m);
        }
        if (l == 0) scnt = min(base, CAPM);
    }
    __syncthreads();
    const int nc = scnt;

    // ---- stage dl[j][px]: one coalesced dist row-segment per candidate ----
    #pragma unroll 1
    for (int j = wv; j < nc; j += 4) {
        int cp = sjw[j];
        int tx = cp & 1023, ty = (cp >> 10) & 1023, jj = cp >> 20;
        unsigned dx = (unsigned)(px - tx);
        float v = 0.0f;
        if (dx < 128u) v = dist[((size_t)jj << 14) + ((r - ty) << 7) + (int)dx];
        dl[j][l] = (_Float16)v;
    }
    __syncthreads();

    // ---- t-loop: one output window per wave-iteration ----
    #pragma unroll 1
    for (int t = wv; t < nc; t += 4) {
        int cpt = sjw[t];
        int kt = cpt >> 20;
        const float* mrow = Msym + kt * NK;
        #pragma unroll
        for (int cch = 0; cch < 3; ++cch) {      // compact (m, tx) pairs
            int j2 = cch * 64 + l;
            if (j2 < nc) {
                int cj = sjw[j2];
                mpk[wv][j2] = int2{__builtin_bit_cast(int, mrow[cj >> 20]),
                                   cj & 1023};
            }
        }
        float num = 0.0f, den = 0.0f;
        #pragma unroll 4
        for (int j = 0; j < nc; ++j) {
            int2 mp = mpk[wv][j];
            float m = __builtin_bit_cast(float, mp.x);
            num = fmaf(m, (float)dl[j][l], num); // dl = 0 where uncovered
            unsigned dxj = (unsigned)(px - mp.y);
            den += (dxj < 128u) ? m : 0.0f;
        }
        unsigned dxk = (unsigned)(px - (cpt & 1023));
        if (dxk < 128u)
            out[((size_t)kt << 14) + ((r - ((cpt >> 10) & 1023)) << 7) + (int)dxk] =
                num / fmaxf(den, EPSV);
    }
}

// -------------------------------------------------------------- launch ----
extern "C" void kernel_launch(void* const* d_in, const int* in_sizes, int n_in,
                              void* d_out, int out_size, void* d_ws, size_t ws_size,
                              hipStream_t stream) {
    const float* x     = (const float*)d_in[0];
    const float* sigma = (const float*)d_in[1];
    const float* c     = (const float*)d_in[2];
    const int*   cent  = (const int*)d_in[3];
    const float* M     = (const float*)d_in[4];
    const float* W1    = (const float*)d_in[5];
    const float* b1    = (const float*)d_in[6];
    const float* W2    = (const float*)d_in[7];
    const float* b2    = (const float*)d_in[8];
    const float* W3    = (const float*)d_in[9];
    const float* b3    = (const float*)d_in[10];
    float* out = (float*)d_out;

    float* ws       = (float*)d_ws;
    float* dist     = ws + WS_DIST;
    float* Msym     = ws + WS_MSYM;
    _Float16* W2f   = (_Float16*)(ws + WS_W2F);
    _Float16* D     = (_Float16*)(ws + WS_D);
    float* center   = ws + WS_CENTER;
    int*   gctr     = (int*)(ws + WS_CTR);
    _Float16* G     = (_Float16*)(ws + WS_G);

    prep_kernel<<<256, 256, 0, stream>>>(M, W1, W2, c, b1, Msym, W2f, D, gctr);
    gfeat_kernel<<<576, 256, 0, stream>>>(x, sigma, W1, G);
    center2_kernel<<<256, 128, 0, stream>>>(G, D, W2, b2, W3, b3, cent, center);
    pix_kernel<<<768, 256, 0, stream>>>(G, D, W2f, cent, b2, W3, b3, center,
                                        gctr, dist);
    merge_kernel<<<2304, 256, 0, stream>>>(dist, cent, Msym, out);
}